// Round 6
// baseline (104.748 us; speedup 1.0000x reference)
//
#include <hip/hip_runtime.h>
#include <hip/hip_fp16.h>

// SAM self-attention. bs=8, C=64, Dqk=32, HW=4096. Inputs f32, output f32.
// fp16 MFMA (f32 accum), KV-split-4 flash attention.
// This round: T13 defer-max — hot path has NO cross-lane shuffles and NO
// rescale; slow path (tile 0 + rare max growth) does the full reduce.
// ws (u16): Qr[8][4096][32] | Kr | Vc[8][64][4096] = 8 MB, then f32 partials.

typedef short          f16x8 __attribute__((ext_vector_type(8)));
typedef float          f32x4 __attribute__((ext_vector_type(4)));
typedef unsigned short u16;

#define HW  4096
#define CC  64
#define DQK 32
#define NBLK 512   // 8 batches * 64 q-blocks
#define THR 8.0f   // defer-max threshold: P <= e^8 fits fp16

__device__ __forceinline__ u16 f2h(float f) {
    __half h = __float2half(f);
    return *reinterpret_cast<u16*>(&h);
}

// ---------------------------------------------------------------------------
// Projection: [wq;wk;wv](128x64) @ X(64x4096) per batch. 4 waves, 64 cols.
// ---------------------------------------------------------------------------
__global__ __launch_bounds__(256) void proj_kernel(
    const float* __restrict__ x,  const float* __restrict__ wq,
    const float* __restrict__ wk, const float* __restrict__ wv,
    u16* __restrict__ Qr, u16* __restrict__ Kr, u16* __restrict__ Vc)
{
    const int b   = blockIdx.x;
    const int n0  = blockIdx.y * 64;
    const int tid = threadIdx.x;

    __shared__ __align__(16) u16 Xt[64][88];   // X^T tile [n][c]

    {
        const int c  = tid >> 2;
        const int nc = (tid & 3) * 16;
        const float* src = x + ((size_t)(b * CC + c) * HW + n0 + nc);
        float fv[16];
        *(f32x4*)(fv)      = *(const f32x4*)(src);
        *(f32x4*)(fv + 4)  = *(const f32x4*)(src + 4);
        *(f32x4*)(fv + 8)  = *(const f32x4*)(src + 8);
        *(f32x4*)(fv + 12) = *(const f32x4*)(src + 12);
        #pragma unroll
        for (int i = 0; i < 16; ++i) Xt[nc + i][c] = f2h(fv[i]);
    }
    __syncthreads();

    const int wave = tid >> 6;
    const int lane = tid & 63;
    const int lr   = lane & 15;
    const int lg   = lane >> 4;
    const int lk   = lg * 8;

    const float* W = (wave == 0) ? wq : (wave == 1) ? wk
                   : (wave == 2) ? wv : (wv + 32 * 64);

    f16x8 a[2][2];
    #pragma unroll
    for (int dt = 0; dt < 2; ++dt)
        #pragma unroll
        for (int h = 0; h < 2; ++h) {
            const float* p = W + (dt * 16 + lr) * 64 + h * 32 + lk;
            f32x4 lo = *(const f32x4*)p, hi = *(const f32x4*)(p + 4);
            u16 t[8];
            #pragma unroll
            for (int j = 0; j < 4; ++j) { t[j] = f2h(lo[j]); t[4 + j] = f2h(hi[j]); }
            a[dt][h] = *(const f16x8*)t;
        }

    const f32x4 fz = {0.f, 0.f, 0.f, 0.f};
    f32x4 acc[2][4];
    #pragma unroll
    for (int dt = 0; dt < 2; ++dt)
        #pragma unroll
        for (int nt = 0; nt < 4; ++nt) acc[dt][nt] = fz;

    #pragma unroll
    for (int nt = 0; nt < 4; ++nt)
        #pragma unroll
        for (int h = 0; h < 2; ++h) {
            f16x8 bx = *(const f16x8*)(&Xt[nt * 16 + lr][h * 32 + lk]);
            #pragma unroll
            for (int dt = 0; dt < 2; ++dt)
                acc[dt][nt] = __builtin_amdgcn_mfma_f32_16x16x32_f16(
                                  a[dt][h], bx, acc[dt][nt], 0, 0, 0);
        }

    if (wave < 2) {
        u16* Out = (wave == 0) ? Qr : Kr;          // [n][32]
        #pragma unroll
        for (int dt = 0; dt < 2; ++dt)
            #pragma unroll
            for (int nt = 0; nt < 4; ++nt) {
                const int n = n0 + nt * 16 + lr;
                const int d = dt * 16 + lg * 4;
                u16 pk[4];
                #pragma unroll
                for (int r = 0; r < 4; ++r) pk[r] = f2h(acc[dt][nt][r]);
                *(uint2*)(Out + ((size_t)(b * HW + n) * DQK + d)) = *(uint2*)pk;
            }
    } else {
        const int cbase = (wave - 2) * 32;          // Vc[c][m]
        #pragma unroll
        for (int dt = 0; dt < 2; ++dt)
            #pragma unroll
            for (int nt = 0; nt < 4; ++nt) {
                const int m = n0 + nt * 16 + lr;
                #pragma unroll
                for (int r = 0; r < 4; ++r) {
                    const int c = cbase + dt * 16 + lg * 4 + r;
                    Vc[(size_t)(b * CC + c) * HW + m] = f2h(acc[dt][nt][r]);
                }
            }
    }
}

// ---------------------------------------------------------------------------
// Flash attention, KV-split S ways, defer-max softmax.
// ---------------------------------------------------------------------------
template<int S>
__global__ __launch_bounds__(256) void attn_kernel(
    const u16* __restrict__ Qr, const u16* __restrict__ Kr,
    const u16* __restrict__ Vc, float* __restrict__ out,
    float* __restrict__ Opart, float* __restrict__ Ml)
{
    const int b    = blockIdx.x;
    const int nb   = blockIdx.y;
    const int sp   = blockIdx.z;
    const int n0   = nb * 64;
    const int tid  = threadIdx.x;
    const int wave = tid >> 6;
    const int lane = tid & 63;
    const int lr   = lane & 15;
    const int lg   = lane >> 4;
    const int lk   = lg * 8;

    __shared__ __align__(16) u16 K_lds[64 * 40];   // [m][d], stride 40 u16
    __shared__ __align__(16) u16 V_lds[64 * 72];   // [c][m], stride 72 u16
    __shared__ __align__(16) u16 P_lds[4][16][88]; // per-wave P

    const int qbase = n0 + wave * 16;
    const f16x8 aq = *(const f16x8*)(Qr + (size_t)(b * HW + qbase + lr) * DQK + lk);

    const f16x8 ones = { 0x3C00, 0x3C00, 0x3C00, 0x3C00,
                         0x3C00, 0x3C00, 0x3C00, 0x3C00 };
    const f32x4 fz = {0.f, 0.f, 0.f, 0.f};

    // staging roles
    const int km = tid >> 2, kc = tid & 3;          // K: 16B pieces
    const int c0 = tid >> 3, ch = tid & 7;          // V: two 16B pieces
    const int c1 = 32 + (tid >> 3);

    const int kvbase = sp * (HW / S);
    const int NT     = HW / S / 64;

    const u16* Kb  = Kr + (size_t)(b * HW + kvbase + km) * DQK + kc * 8;
    const u16* Vb0 = Vc + (size_t)(b * CC + c0) * HW + kvbase + ch * 8;
    const u16* Vb1 = Vc + (size_t)(b * CC + c1) * HW + kvbase + ch * 8;

    f16x8 kreg  = *(const f16x8*)(Kb);
    f16x8 v0reg = *(const f16x8*)(Vb0);
    f16x8 v1reg = *(const f16x8*)(Vb1);

    f32x4 o[4];
    #pragma unroll
    for (int ct = 0; ct < 4; ++ct) o[ct] = fz;
    float mrow[4] = {-1e30f, -1e30f, -1e30f, -1e30f};
    float lrow[4] = {0.f, 0.f, 0.f, 0.f};

    for (int t = 0; t < NT; ++t) {
        __syncthreads();                             // prev compute done
        *(f16x8*)&K_lds[km * 40 + kc * 8] = kreg;
        *(f16x8*)&V_lds[c0 * 72 + ch * 8] = v0reg;
        *(f16x8*)&V_lds[c1 * 72 + ch * 8] = v1reg;
        if (t + 1 < NT) {                            // prefetch next tile
            kreg  = *(const f16x8*)(Kb  + (size_t)(t + 1) * 64 * DQK);
            v0reg = *(const f16x8*)(Vb0 + (t + 1) * 64);
            v1reg = *(const f16x8*)(Vb1 + (t + 1) * 64);
        }
        __syncthreads();                             // LDS ready

        // ---- S = Q K^T ----  s[mt][r] = S[q=lg*4+r][m=mt*16+lr]
        f32x4 s[4];
        #pragma unroll
        for (int mt = 0; mt < 4; ++mt) {
            f16x8 bk = *(const f16x8*)&K_lds[(mt * 16 + lr) * 40 + lk];
            s[mt] = __builtin_amdgcn_mfma_f32_16x16x32_f16(aq, bk, fz, 0, 0, 0);
        }

        // ---- defer-max softmax (T13): lane-local max only in hot path ----
        float lm[4];
        #pragma unroll
        for (int r = 0; r < 4; ++r)
            lm[r] = fmaxf(fmaxf(s[0][r], s[1][r]), fmaxf(s[2][r], s[3][r]));

        bool need = (lm[0] > mrow[0] + THR) | (lm[1] > mrow[1] + THR) |
                    (lm[2] > mrow[2] + THR) | (lm[3] > mrow[3] + THR);
        if (__any(need)) {
            // slow path: full cross-lane reduce + rescale (tile 0 + rare growth)
            #pragma unroll
            for (int r = 0; r < 4; ++r) {
                float v = lm[r];
                v = fmaxf(v, __shfl_xor(v, 1, 64));
                v = fmaxf(v, __shfl_xor(v, 2, 64));
                v = fmaxf(v, __shfl_xor(v, 4, 64));
                v = fmaxf(v, __shfl_xor(v, 8, 64));
                if (v > mrow[r]) {
                    float alpha = __expf(mrow[r] - v);
                    #pragma unroll
                    for (int ct = 0; ct < 4; ++ct) o[ct][r] *= alpha;
                    lrow[r] *= alpha;
                    mrow[r]  = v;
                }
            }
        }

        // P = exp(S - m) -> fp16 -> per-wave LDS (P <= e^THR, fp16-safe)
        #pragma unroll
        for (int mt = 0; mt < 4; ++mt)
            #pragma unroll
            for (int r = 0; r < 4; ++r) {
                float p = __expf(s[mt][r] - mrow[r]);
                P_lds[wave][lg * 4 + r][mt * 16 + lr] = f2h(p);
            }

        f16x8 pa0 = *(const f16x8*)(&P_lds[wave][lr][lk]);
        f16x8 pa1 = *(const f16x8*)(&P_lds[wave][lr][32 + lk]);

        // row sums via MFMA-with-ones (consistent with fp16-rounded P)
        f32x4 rs = __builtin_amdgcn_mfma_f32_16x16x32_f16(pa0, ones, fz, 0, 0, 0);
        rs = __builtin_amdgcn_mfma_f32_16x16x32_f16(pa1, ones, rs, 0, 0, 0);
        #pragma unroll
        for (int r = 0; r < 4; ++r) lrow[r] += rs[r];

        // ---- O += P V^T ----
        #pragma unroll
        for (int ct = 0; ct < 4; ++ct) {
            const int c = ct * 16 + lr;
            f16x8 bv0 = *(const f16x8*)&V_lds[c * 72 + lk];
            f16x8 bv1 = *(const f16x8*)&V_lds[c * 72 + 32 + lk];
            o[ct] = __builtin_amdgcn_mfma_f32_16x16x32_f16(pa0, bv0, o[ct], 0, 0, 0);
            o[ct] = __builtin_amdgcn_mfma_f32_16x16x32_f16(pa1, bv1, o[ct], 0, 0, 0);
        }
    }

    if constexpr (S == 1) {
        #pragma unroll
        for (int ct = 0; ct < 4; ++ct) {
            const int c = ct * 16 + lr;
            f32x4 st;
            #pragma unroll
            for (int r = 0; r < 4; ++r) st[r] = o[ct][r] / lrow[r];
            *(f32x4*)(out + (size_t)(b * CC + c) * HW + qbase + lg * 4) = st;
        }
    } else {
        const int bnb  = b * 64 + nb;
        const int qloc = wave * 16 + lg * 4;
        float* Op = Opart + ((size_t)(sp * NBLK + bnb) * 64) * 64;
        #pragma unroll
        for (int ct = 0; ct < 4; ++ct) {
            const int c = ct * 16 + lr;
            *(f32x4*)(Op + (size_t)c * 64 + qloc) = o[ct];
        }
        if (lr == 0) {
            float* Mp = Ml + (size_t)(sp * NBLK + bnb) * 128;
            #pragma unroll
            for (int r = 0; r < 4; ++r) {
                Mp[qloc + r]      = mrow[r];
                Mp[64 + qloc + r] = lrow[r];
            }
        }
    }
}

// ---------------------------------------------------------------------------
// Combine S partials: out = sum_s e^{m_s-M} O_s / sum_s l_s e^{m_s-M}
// ---------------------------------------------------------------------------
template<int S>
__global__ __launch_bounds__(256) void combine_kernel(
    const float* __restrict__ Opart, const float* __restrict__ Ml,
    float* __restrict__ out)
{
    const int bnb = blockIdx.x;
    const int b = bnb >> 6, nb = bnb & 63;
    const int tid = threadIdx.x;
    const int c  = tid >> 2;
    const int q0 = (tid & 3) * 16;

    #pragma unroll
    for (int qq = 0; qq < 16; qq += 4) {
        const int q = q0 + qq;
        f32x4 ms[S], ls[S];
        #pragma unroll
        for (int s = 0; s < S; ++s) {
            const float* Mp = Ml + (size_t)(s * NBLK + bnb) * 128;
            ms[s] = *(const f32x4*)(Mp + q);
            ls[s] = *(const f32x4*)(Mp + 64 + q);
        }
        f32x4 M = ms[0];
        #pragma unroll
        for (int s = 1; s < S; ++s)
            #pragma unroll
            for (int j = 0; j < 4; ++j) M[j] = fmaxf(M[j], ms[s][j]);
        f32x4 den = {0.f, 0.f, 0.f, 0.f};
        f32x4 w[S];
        #pragma unroll
        for (int s = 0; s < S; ++s)
            #pragma unroll
            for (int j = 0; j < 4; ++j) {
                w[s][j] = __expf(ms[s][j] - M[j]);
                den[j] += ls[s][j] * w[s][j];
            }
        f32x4 acc = {0.f, 0.f, 0.f, 0.f};
        #pragma unroll
        for (int s = 0; s < S; ++s) {
            f32x4 Ov = *(const f32x4*)(Opart +
                          ((size_t)(s * NBLK + bnb) * 64 + c) * 64 + q);
            #pragma unroll
            for (int j = 0; j < 4; ++j) acc[j] += w[s][j] * Ov[j];
        }
        #pragma unroll
        for (int j = 0; j < 4; ++j) acc[j] /= den[j];
        *(f32x4*)(out + (size_t)(b * CC + c) * HW + nb * 64 + q) = acc;
    }
}

extern "C" void kernel_launch(void* const* d_in, const int* in_sizes, int n_in,
                              void* d_out, int out_size, void* d_ws, size_t ws_size,
                              hipStream_t stream)
{
    const float* x  = (const float*)d_in[0];
    const float* wq = (const float*)d_in[1];
    const float* wk = (const float*)d_in[2];
    const float* wv = (const float*)d_in[3];
    u16* ws  = (u16*)d_ws;
    u16* Qr  = ws;                              // [8][4096][32]
    u16* Kr  = ws + (size_t)8 * HW * DQK;       // [8][4096][32]
    u16* Vc  = ws + (size_t)16 * HW * DQK;      // [8][64][4096]
    float* Opart = (float*)(ws + (size_t)4194304);           // after 8MB
    float* out = (float*)d_out;

    proj_kernel<<<dim3(8, 64), 256, 0, stream>>>(x, wq, wk, wv, Qr, Kr, Vc);

    const size_t qkv_b   = 8ull * 1024 * 1024;
    const size_t opart_b = (size_t)NBLK * 64 * 64 * 4;       // per split: 8.39MB
    const size_t ml_b    = (size_t)NBLK * 128 * 4;           // per split: 256KB

    if (ws_size >= qkv_b + 4 * (opart_b + ml_b)) {
        float* Ml = Opart + 4ull * NBLK * 64 * 64;
        attn_kernel<4><<<dim3(8, 64, 4), 256, 0, stream>>>(Qr, Kr, Vc, out, Opart, Ml);
        combine_kernel<4><<<NBLK, 256, 0, stream>>>(Opart, Ml, out);
    } else if (ws_size >= qkv_b + 2 * (opart_b + ml_b)) {
        float* Ml = Opart + 2ull * NBLK * 64 * 64;
        attn_kernel<2><<<dim3(8, 64, 2), 256, 0, stream>>>(Qr, Kr, Vc, out, Opart, Ml);
        combine_kernel<2><<<NBLK, 256, 0, stream>>>(Opart, Ml, out);
    } else {
        attn_kernel<1><<<dim3(8, 64, 1), 256, 0, stream>>>(Qr, Kr, Vc, out, nullptr, nullptr);
    }
}

// Round 8
// 76.506 us; speedup vs baseline: 1.3692x; 1.3692x over previous
//
#include <hip/hip_runtime.h>
#include <hip/hip_fp16.h>

// SAM self-attention. bs=8, C=64, Dqk=32, HW=4096. Inputs f32, output f32.
// fp16 MFMA (f32 accum), KV-split flash attention.
// LDS-traffic restructure: 32 q/wave (128/block), swapped QK^T with
// bit-shuffled K staging so P packs in-register (cvt_pkrtz) directly
// into PV A-fragments. P_lds eliminated; V/K LDS reads per q halved.

typedef short          f16x8 __attribute__((ext_vector_type(8)));
typedef float          f32x4 __attribute__((ext_vector_type(4)));
typedef unsigned short u16;
typedef unsigned int   u32;

#define HW  4096
#define CC  64
#define DQK 32
#define NBLK2 256   // 8 batches * 32 q-blocks (128 q each)
#define THR 8.0f    // defer-max threshold: P <= e^8 fits fp16

__device__ __forceinline__ u16 f2h(float f) {
    __half h = __float2half(f);
    return *reinterpret_cast<u16*>(&h);
}
__device__ __forceinline__ u32 pk2(float a, float b) {
    auto r = __builtin_amdgcn_cvt_pkrtz(a, b);   // __fp16 ext_vector(2)
    u32 u; __builtin_memcpy(&u, &r, 4); return u;
}

// ---------------------------------------------------------------------------
// Projection: [wq;wk;wv](128x64) @ X(64x4096) per batch. 4 waves, 64 cols.
// ---------------------------------------------------------------------------
__global__ __launch_bounds__(256) void proj_kernel(
    const float* __restrict__ x,  const float* __restrict__ wq,
    const float* __restrict__ wk, const float* __restrict__ wv,
    u16* __restrict__ Qr, u16* __restrict__ Kr, u16* __restrict__ Vc)
{
    const int b   = blockIdx.x;
    const int n0  = blockIdx.y * 64;
    const int tid = threadIdx.x;

    __shared__ __align__(16) u16 Xt[64][88];   // X^T tile [n][c]

    {
        const int c  = tid >> 2;
        const int nc = (tid & 3) * 16;
        const float* src = x + ((size_t)(b * CC + c) * HW + n0 + nc);
        float fv[16];
        *(f32x4*)(fv)      = *(const f32x4*)(src);
        *(f32x4*)(fv + 4)  = *(const f32x4*)(src + 4);
        *(f32x4*)(fv + 8)  = *(const f32x4*)(src + 8);
        *(f32x4*)(fv + 12) = *(const f32x4*)(src + 12);
        #pragma unroll
        for (int i = 0; i < 16; ++i) Xt[nc + i][c] = f2h(fv[i]);
    }
    __syncthreads();

    const int wave = tid >> 6;
    const int lane = tid & 63;
    const int lr   = lane & 15;
    const int lg   = lane >> 4;
    const int lk   = lg * 8;

    const float* W = (wave == 0) ? wq : (wave == 1) ? wk
                   : (wave == 2) ? wv : (wv + 32 * 64);

    f16x8 a[2][2];
    #pragma unroll
    for (int dt = 0; dt < 2; ++dt)
        #pragma unroll
        for (int h = 0; h < 2; ++h) {
            const float* p = W + (dt * 16 + lr) * 64 + h * 32 + lk;
            f32x4 lo = *(const f32x4*)p, hi = *(const f32x4*)(p + 4);
            u16 t[8];
            #pragma unroll
            for (int j = 0; j < 4; ++j) { t[j] = f2h(lo[j]); t[4 + j] = f2h(hi[j]); }
            a[dt][h] = *(const f16x8*)t;
        }

    const f32x4 fz = {0.f, 0.f, 0.f, 0.f};
    f32x4 acc[2][4];
    #pragma unroll
    for (int dt = 0; dt < 2; ++dt)
        #pragma unroll
        for (int nt = 0; nt < 4; ++nt) acc[dt][nt] = fz;

    #pragma unroll
    for (int nt = 0; nt < 4; ++nt)
        #pragma unroll
        for (int h = 0; h < 2; ++h) {
            f16x8 bx = *(const f16x8*)(&Xt[nt * 16 + lr][h * 32 + lk]);
            #pragma unroll
            for (int dt = 0; dt < 2; ++dt)
                acc[dt][nt] = __builtin_amdgcn_mfma_f32_16x16x32_f16(
                                  a[dt][h], bx, acc[dt][nt], 0, 0, 0);
        }

    if (wave < 2) {
        u16* Out = (wave == 0) ? Qr : Kr;          // [n][32]
        #pragma unroll
        for (int dt = 0; dt < 2; ++dt)
            #pragma unroll
            for (int nt = 0; nt < 4; ++nt) {
                const int n = n0 + nt * 16 + lr;
                const int d = dt * 16 + lg * 4;
                u16 pkk[4];
                #pragma unroll
                for (int r = 0; r < 4; ++r) pkk[r] = f2h(acc[dt][nt][r]);
                *(uint2*)(Out + ((size_t)(b * HW + n) * DQK + d)) = *(uint2*)pkk;
            }
    } else {
        const int cbase = (wave - 2) * 32;          // Vc[c][m]
        #pragma unroll
        for (int dt = 0; dt < 2; ++dt)
            #pragma unroll
            for (int nt = 0; nt < 4; ++nt) {
                const int m = n0 + nt * 16 + lr;
                #pragma unroll
                for (int r = 0; r < 4; ++r) {
                    const int c = cbase + dt * 16 + lg * 4 + r;
                    Vc[(size_t)(b * CC + c) * HW + m] = f2h(acc[dt][nt][r]);
                }
            }
    }
}

// ---------------------------------------------------------------------------
// Flash attention, KV-split S ways. Block = 128 q (4 waves x 32), KVBLK=64.
// Swapped QK^T: mfma(K,Q) -> lane holds P[q=lr][m-subset]; K staged with
// bit-shuffled rows (m = a.32+lg.8+b.4+r stored at row a.32+b.16+lg.4+r) so
// cvt_pkrtz packs P directly into PV A-fragments. No P_lds, no redistribution.
// ---------------------------------------------------------------------------
template<int S>
__global__ __launch_bounds__(256, 4) void attn_kernel(
    const u16* __restrict__ Qr, const u16* __restrict__ Kr,
    const u16* __restrict__ Vc, float* __restrict__ out,
    float* __restrict__ Opart, float* __restrict__ Ml)
{
    const int b    = blockIdx.x;
    const int nb   = blockIdx.y;
    const int sp   = blockIdx.z;
    const int n0   = nb * 128;
    const int tid  = threadIdx.x;
    const int wave = tid >> 6;
    const int lane = tid & 63;
    const int lr   = lane & 15;
    const int lg   = lane >> 4;
    const int lk   = lg * 8;

    __shared__ __align__(16) u16 K_lds[64 * 40];   // [row][d], rows bit-shuffled
    __shared__ __align__(16) u16 V_lds[64 * 72];   // [c][m]

    const int qb = n0 + wave * 32;
    const f16x8 aq0 = *(const f16x8*)(Qr + (size_t)(b * HW + qb + lr) * DQK + lk);
    const f16x8 aq1 = *(const f16x8*)(Qr + (size_t)(b * HW + qb + 16 + lr) * DQK + lk);

    const f16x8 ones = { 0x3C00, 0x3C00, 0x3C00, 0x3C00,
                         0x3C00, 0x3C00, 0x3C00, 0x3C00 };
    const f32x4 fz = {0.f, 0.f, 0.f, 0.f};

    // staging roles
    const int km = tid >> 2, kc = tid & 3;          // K: 16B pieces
    const int krow = (km & 32) | (((km >> 2) & 1) << 4)
                   | (((km >> 3) & 3) << 2) | (km & 3);   // bit-shuffled dst row
    const int c0 = tid >> 3, ch = tid & 7;          // V: two 16B pieces
    const int c1 = 32 + c0;

    const int kvbase = sp * (HW / S);
    const int NT     = HW / S / 64;

    const u16* Kb  = Kr + (size_t)(b * HW + kvbase + km) * DQK + kc * 8;
    const u16* Vb0 = Vc + (size_t)(b * CC + c0) * HW + kvbase + ch * 8;
    const u16* Vb1 = Vc + (size_t)(b * CC + c1) * HW + kvbase + ch * 8;

    f16x8 kreg  = *(const f16x8*)(Kb);
    f16x8 v0reg = *(const f16x8*)(Vb0);
    f16x8 v1reg = *(const f16x8*)(Vb1);

    f32x4 o[2][4];
    #pragma unroll
    for (int qs = 0; qs < 2; ++qs)
        #pragma unroll
        for (int ct = 0; ct < 4; ++ct) o[qs][ct] = fz;
    f32x4 lrow[2] = {fz, fz};                 // q = 4*lg + r (o-layout)
    float mrow[2] = {-1e30f, -1e30f};         // q = lr      (s-layout)

    for (int t = 0; t < NT; ++t) {
        __syncthreads();
        *(f16x8*)&K_lds[krow * 40 + kc * 8] = kreg;
        *(f16x8*)&V_lds[c0 * 72 + ch * 8]   = v0reg;
        *(f16x8*)&V_lds[c1 * 72 + ch * 8]   = v1reg;
        if (t + 1 < NT) {
            kreg  = *(const f16x8*)(Kb  + (size_t)(t + 1) * 64 * DQK);
            v0reg = *(const f16x8*)(Vb0 + (t + 1) * 64);
            v1reg = *(const f16x8*)(Vb1 + (t + 1) * 64);
        }
        __syncthreads();

        // ---- S^T = K Q^T : lane holds s[mt][r] = S[q=lr][m=32*(mt>>1)+8*lg+4*(mt&1)+r]
        f32x4 s0[4], s1[4];
        #pragma unroll
        for (int mt = 0; mt < 4; ++mt) {
            f16x8 kf = *(const f16x8*)&K_lds[(mt * 16 + lr) * 40 + lk];
            s0[mt] = __builtin_amdgcn_mfma_f32_16x16x32_f16(kf, aq0, fz, 0, 0, 0);
            s1[mt] = __builtin_amdgcn_mfma_f32_16x16x32_f16(kf, aq1, fz, 0, 0, 0);
        }

        // ---- defer-max (lane-local check only in hot path) ----
        float lm0 = s0[0][0], lm1 = s1[0][0];
        #pragma unroll
        for (int mt = 0; mt < 4; ++mt)
            #pragma unroll
            for (int r = 0; r < 4; ++r) {
                if (mt || r) {
                    lm0 = fmaxf(lm0, s0[mt][r]);
                    lm1 = fmaxf(lm1, s1[mt][r]);
                }
            }
        if (__any((lm0 > mrow[0] + THR) | (lm1 > mrow[1] + THR))) {
            #pragma unroll
            for (int qs = 0; qs < 2; ++qs) {
                float v = qs ? lm1 : lm0;
                v = fmaxf(v, __shfl_xor(v, 16, 64));
                v = fmaxf(v, __shfl_xor(v, 32, 64));
                float mnew  = fmaxf(mrow[qs], v);
                float alpha = __expf(mrow[qs] - mnew);   // <=1; 0 on first tile
                mrow[qs] = mnew;
                f32x4 al;                                 // translate lr->4lg+r layout
                #pragma unroll
                for (int r = 0; r < 4; ++r) al[r] = __shfl(alpha, 4 * lg + r, 64);
                #pragma unroll
                for (int ct = 0; ct < 4; ++ct)
                    #pragma unroll
                    for (int r = 0; r < 4; ++r) o[qs][ct][r] *= al[r];
                #pragma unroll
                for (int r = 0; r < 4; ++r) lrow[qs][r] *= al[r];
            }
        }

        // ---- P = exp(S - m), packed in-register into PV A-fragments ----
        f16x8 pa[2][2];
        #pragma unroll
        for (int qs = 0; qs < 2; ++qs) {
            const float m = mrow[qs];
            #pragma unroll
            for (int h = 0; h < 2; ++h) {
                u32 w[4];
                #pragma unroll
                for (int half = 0; half < 2; ++half) {
                    const f32x4& sv = qs ? s1[2 * h + half] : s0[2 * h + half];
                    float p0 = __expf(sv[0] - m), p1 = __expf(sv[1] - m);
                    float p2 = __expf(sv[2] - m), p3 = __expf(sv[3] - m);
                    w[2 * half]     = pk2(p0, p1);
                    w[2 * half + 1] = pk2(p2, p3);
                }
                __builtin_memcpy(&pa[qs][h], w, 16);
            }
        }

        // row sums via MFMA-with-ones (lands in o-layout q=4lg+r)
        #pragma unroll
        for (int qs = 0; qs < 2; ++qs) {
            f32x4 rs = __builtin_amdgcn_mfma_f32_16x16x32_f16(pa[qs][0], ones, fz, 0, 0, 0);
            rs = __builtin_amdgcn_mfma_f32_16x16x32_f16(pa[qs][1], ones, rs, 0, 0, 0);
            #pragma unroll
            for (int r = 0; r < 4; ++r) lrow[qs][r] += rs[r];
        }

        // ---- O += P V^T : V frags shared by both q-subtiles ----
        #pragma unroll
        for (int ct = 0; ct < 4; ++ct) {
            const int c = ct * 16 + lr;
            f16x8 bv0 = *(const f16x8*)&V_lds[c * 72 + lk];
            f16x8 bv1 = *(const f16x8*)&V_lds[c * 72 + 32 + lk];
            o[0][ct] = __builtin_amdgcn_mfma_f32_16x16x32_f16(pa[0][0], bv0, o[0][ct], 0, 0, 0);
            o[0][ct] = __builtin_amdgcn_mfma_f32_16x16x32_f16(pa[0][1], bv1, o[0][ct], 0, 0, 0);
            o[1][ct] = __builtin_amdgcn_mfma_f32_16x16x32_f16(pa[1][0], bv0, o[1][ct], 0, 0, 0);
            o[1][ct] = __builtin_amdgcn_mfma_f32_16x16x32_f16(pa[1][1], bv1, o[1][ct], 0, 0, 0);
        }
    }

    if constexpr (S == 1) {
        #pragma unroll
        for (int qs = 0; qs < 2; ++qs)
            #pragma unroll
            for (int ct = 0; ct < 4; ++ct) {
                const int c = ct * 16 + lr;
                f32x4 st;
                #pragma unroll
                for (int r = 0; r < 4; ++r) st[r] = o[qs][ct][r] / lrow[qs][r];
                *(f32x4*)(out + (size_t)(b * CC + c) * HW + qb + qs * 16 + lg * 4) = st;
            }
    } else {
        const int bnb = b * 32 + nb;
        float* Op = Opart + ((size_t)(sp * NBLK2 + bnb) * 64) * 128;
        #pragma unroll
        for (int qs = 0; qs < 2; ++qs)
            #pragma unroll
            for (int ct = 0; ct < 4; ++ct) {
                const int c    = ct * 16 + lr;
                const int qloc = wave * 32 + qs * 16 + lg * 4;
                *(f32x4*)(Op + (size_t)c * 128 + qloc) = o[qs][ct];
            }
        float* Mp = Ml + (size_t)(sp * NBLK2 + bnb) * 256;
        if (lg == 0) {
            Mp[wave * 32 + lr]      = mrow[0];
            Mp[wave * 32 + 16 + lr] = mrow[1];
        }
        if (lr == 0) {
            #pragma unroll
            for (int qs = 0; qs < 2; ++qs)
                #pragma unroll
                for (int r = 0; r < 4; ++r)
                    Mp[128 + wave * 32 + qs * 16 + 4 * lg + r] = lrow[qs][r];
        }
    }
}

// ---------------------------------------------------------------------------
// Combine S partials: out = sum_s e^{m_s-M} O_s / sum_s l_s e^{m_s-M}
// Blocks of 128 q x 64 c.
// ---------------------------------------------------------------------------
template<int S>
__global__ __launch_bounds__(256) void combine_kernel(
    const float* __restrict__ Opart, const float* __restrict__ Ml,
    float* __restrict__ out)
{
    const int bnb = blockIdx.x;           // 0..255
    const int b = bnb >> 5, nb = bnb & 31;
    const int tid = threadIdx.x;
    const int c  = tid >> 2;
    const int q0 = (tid & 3) * 32;

    #pragma unroll
    for (int qq = 0; qq < 32; qq += 4) {
        const int q = q0 + qq;
        f32x4 ms[S], ls[S];
        #pragma unroll
        for (int s = 0; s < S; ++s) {
            const float* Mp = Ml + (size_t)(s * NBLK2 + bnb) * 256;
            ms[s] = *(const f32x4*)(Mp + q);
            ls[s] = *(const f32x4*)(Mp + 128 + q);
        }
        f32x4 M = ms[0];
        #pragma unroll
        for (int s = 1; s < S; ++s)
            #pragma unroll
            for (int j = 0; j < 4; ++j) M[j] = fmaxf(M[j], ms[s][j]);
        f32x4 den = {0.f, 0.f, 0.f, 0.f};
        f32x4 w[S];
        #pragma unroll
        for (int s = 0; s < S; ++s)
            #pragma unroll
            for (int j = 0; j < 4; ++j) {
                w[s][j] = __expf(ms[s][j] - M[j]);
                den[j] += ls[s][j] * w[s][j];
            }
        f32x4 acc = {0.f, 0.f, 0.f, 0.f};
        #pragma unroll
        for (int s = 0; s < S; ++s) {
            f32x4 Ov = *(const f32x4*)(Opart +
                          ((size_t)(s * NBLK2 + bnb) * 64 + c) * 128 + q);
            #pragma unroll
            for (int j = 0; j < 4; ++j) acc[j] += w[s][j] * Ov[j];
        }
        #pragma unroll
        for (int j = 0; j < 4; ++j) acc[j] /= den[j];
        *(f32x4*)(out + (size_t)(b * CC + c) * HW + nb * 128 + q) = acc;
    }
}

extern "C" void kernel_launch(void* const* d_in, const int* in_sizes, int n_in,
                              void* d_out, int out_size, void* d_ws, size_t ws_size,
                              hipStream_t stream)
{
    const float* x  = (const float*)d_in[0];
    const float* wq = (const float*)d_in[1];
    const float* wk = (const float*)d_in[2];
    const float* wv = (const float*)d_in[3];
    u16* ws  = (u16*)d_ws;
    u16* Qr  = ws;                              // [8][4096][32]
    u16* Kr  = ws + (size_t)8 * HW * DQK;       // [8][4096][32]
    u16* Vc  = ws + (size_t)16 * HW * DQK;      // [8][64][4096]
    float* Opart = (float*)(ws + (size_t)4194304);           // after 8MB
    float* out = (float*)d_out;

    proj_kernel<<<dim3(8, 64), 256, 0, stream>>>(x, wq, wk, wv, Qr, Kr, Vc);

    const size_t qkv_b   = 8ull * 1024 * 1024;
    const size_t opart_b = (size_t)NBLK2 * 64 * 128 * 4;     // per split: 8.39MB
    const size_t ml_b    = (size_t)NBLK2 * 256 * 4;          // per split: 256KB

    if (ws_size >= qkv_b + 4 * (opart_b + ml_b)) {
        float* Ml = Opart + 4ull * NBLK2 * 64 * 128;
        attn_kernel<4><<<dim3(8, 32, 4), 256, 0, stream>>>(Qr, Kr, Vc, out, Opart, Ml);
        combine_kernel<4><<<NBLK2, 256, 0, stream>>>(Opart, Ml, out);
    } else if (ws_size >= qkv_b + 2 * (opart_b + ml_b)) {
        float* Ml = Opart + 2ull * NBLK2 * 64 * 128;
        attn_kernel<2><<<dim3(8, 32, 2), 256, 0, stream>>>(Qr, Kr, Vc, out, Opart, Ml);
        combine_kernel<2><<<NBLK2, 256, 0, stream>>>(Opart, Ml, out);
    } else {
        attn_kernel<1><<<dim3(8, 32, 1), 256, 0, stream>>>(Qr, Kr, Vc, out, nullptr, nullptr);
    }
}